// Round 1
// baseline (1016.376 us; speedup 1.0000x reference)
//
#include <hip/hip_runtime.h>
#include <math.h>

// Problem constants
#define Bb 4
#define Ss 4096
#define Hh 1024
#define Mm 1024
#define Ee 16
#define CAPk 512            // ceil(2.0 * 4096 / 16)

typedef unsigned short u16;
typedef __attribute__((ext_vector_type(8))) short short8;
typedef __attribute__((ext_vector_type(4))) float floatx4;
typedef __attribute__((ext_vector_type(4))) unsigned short ushort4v;

__device__ __forceinline__ float silu_f(float x) {
    return x / (1.0f + expf(-x));
}

// fp32 -> bf16 (RNE)
__device__ __forceinline__ u16 f2b(float x) {
    union { float f; unsigned u; } v; v.f = x;
    unsigned r = (v.u + 0x7fffu + ((v.u >> 16) & 1u)) >> 16;
    return (u16)r;
}

// async 16B global->LDS (wave-uniform LDS base + lane*16)
__device__ __forceinline__ void gl_lds16(const void* g, void* l) {
    __builtin_amdgcn_global_load_lds((const __attribute__((address_space(1))) void*)g,
                                     (__attribute__((address_space(3))) void*)l, 16, 0, 0);
}

// ---------------- router ----------------

// Skinny GEMM: scores[b,e,s] = sigmoid(tlogit[b,e] + hsu[token,:] . gw2[:,e])
// tlogit (timestep . gate_w first half) computed inline per wave (4 experts).
// 64 tokens/block (256 blocks), K chunked by 64 via global_load_lds w16.
__global__ __launch_bounds__(256)
void router_scores(const float* __restrict__ hsu,
                   const float* __restrict__ gate_w,
                   const float* __restrict__ timestep,
                   float* __restrict__ scores) {
    __shared__ float Xs[64 * 64];   // 16 KB, swizzled 16B chunks
    __shared__ float Gs[64 * 16];   // 4 KB
    const int t = threadIdx.x;
    const int row0 = blockIdx.x * 64;        // token base (never crosses b: 4096%64==0)
    const int b = row0 >> 12;
    const int wave = t >> 6, lane = t & 63;
    const int e0 = wave * 4;
    const float* gw2 = gate_w + (size_t)Hh * Ee;   // [k][16] second-half rows

    // inline tlogit for this wave's 4 experts
    float tl0 = 0.f, tl1 = 0.f, tl2 = 0.f, tl3 = 0.f;
    {
        const float* tsrow = timestep + (size_t)b * Hh;
#pragma unroll
        for (int j = 0; j < 16; ++j) {
            int h = lane + 64 * j;
            float tv = tsrow[h];
            const float* gw = gate_w + (size_t)h * Ee + e0;
            tl0 += tv * gw[0]; tl1 += tv * gw[1]; tl2 += tv * gw[2]; tl3 += tv * gw[3];
        }
#pragma unroll
        for (int off = 32; off; off >>= 1) {
            tl0 += __shfl_xor(tl0, off); tl1 += __shfl_xor(tl1, off);
            tl2 += __shfl_xor(tl2, off); tl3 += __shfl_xor(tl3, off);
        }
    }

    float acc0 = 0.f, acc1 = 0.f, acc2 = 0.f, acc3 = 0.f;

    for (int k0 = 0; k0 < Hh; k0 += 64) {
        __syncthreads();
#pragma unroll
        for (int r = 0; r < 4; ++r) {
            int tok = r * 16 + (t >> 4);
            int cslot = t & 15;                 // dest 16B slot within row
            int g = cslot ^ (tok & 15);         // source chunk (swizzle via source)
            const float* src = hsu + (size_t)(row0 + tok) * Hh + k0 + g * 4;
            char* dst = (char*)Xs + r * 4096 + wave * 1024;   // wave-uniform
            gl_lds16(src, dst);
        }
        {
            const float* src = gw2 + (size_t)k0 * Ee + t * 4;
            char* dst = (char*)Gs + wave * 1024;
            gl_lds16(src, dst);
        }
        __syncthreads();
#pragma unroll
        for (int kk = 0; kk < 64; kk += 4) {
            int slot = (kk >> 2) ^ (lane & 15);
            float4 a = *(const float4*)&Xs[lane * 64 + slot * 4];
            float4 g0 = *(const float4*)&Gs[(kk + 0) * Ee + e0];
            float4 g1 = *(const float4*)&Gs[(kk + 1) * Ee + e0];
            float4 g2 = *(const float4*)&Gs[(kk + 2) * Ee + e0];
            float4 g3 = *(const float4*)&Gs[(kk + 3) * Ee + e0];
            acc0 += a.x * g0.x; acc0 += a.y * g1.x; acc0 += a.z * g2.x; acc0 += a.w * g3.x;
            acc1 += a.x * g0.y; acc1 += a.y * g1.y; acc1 += a.z * g2.y; acc1 += a.w * g3.y;
            acc2 += a.x * g0.z; acc2 += a.y * g1.z; acc2 += a.z * g2.z; acc2 += a.w * g3.z;
            acc3 += a.x * g0.w; acc3 += a.y * g1.w; acc3 += a.z * g2.w; acc3 += a.w * g3.w;
        }
    }
    const int s = (row0 + lane) & (Ss - 1);
    float l0 = acc0 + tl0;
    float l1 = acc1 + tl1;
    float l2 = acc2 + tl2;
    float l3 = acc3 + tl3;
    scores[((size_t)(b * Ee + e0 + 0)) * Ss + s] = 1.f / (1.f + expf(-l0));
    scores[((size_t)(b * Ee + e0 + 1)) * Ss + s] = 1.f / (1.f + expf(-l1));
    scores[((size_t)(b * Ee + e0 + 2)) * Ss + s] = 1.f / (1.f + expf(-l2));
    scores[((size_t)(b * Ee + e0 + 3)) * Ss + s] = 1.f / (1.f + expf(-l3));
}

// Radix top-k with wave-parallel suffix scans (no serial t0 loops).
__global__ __launch_bounds__(256)
void topk_kernel(const float* __restrict__ scores,
                 int* __restrict__ sel_idx,
                 float* __restrict__ sel_gate) {
    const int be = blockIdx.x;
    const float* sc = scores + (size_t)be * Ss;
    const int t = threadIdx.x;
    const int lane = t & 63, w = t >> 6;
    __shared__ unsigned hist[256];
    __shared__ unsigned wtot[4];
    __shared__ unsigned sh_prefix;
    __shared__ int sh_need;
    __shared__ unsigned cnt_gt;

    unsigned vu[16];
#pragma unroll
    for (int i = 0; i < 16; ++i) vu[i] = __float_as_uint(sc[t * 16 + i]);

    unsigned prefix = 0;
    int need = CAPk;
    for (int pass = 0; pass < 4; ++pass) {
        const int shift = 24 - 8 * pass;
        hist[t] = 0;
        __syncthreads();
#pragma unroll
        for (int i = 0; i < 16; ++i) {
            unsigned u = vu[i];
            bool ok = (pass == 0) || ((u >> (shift + 8)) == prefix);
            if (ok) atomicAdd(&hist[(u >> shift) & 255u], 1u);
        }
        __syncthreads();
        unsigned hval = hist[t];
        unsigned s = hval;
        // intra-wave inclusive suffix scan (bin t covers [t .. wave_end])
#pragma unroll
        for (int d = 1; d < 64; d <<= 1) {
            unsigned o = __shfl_down(s, d);
            if (lane + d < 64) s += o;
        }
        if (lane == 0) wtot[w] = s;   // wave total
        __syncthreads();
#pragma unroll
        for (int w2 = 0; w2 < 4; ++w2)
            if (w2 > w) s += wtot[w2];
        // s = S[t] = sum_{j>=t} hist[j]; exactly one t satisfies the bracket
        unsigned Snext = s - hval;
        if (s >= (unsigned)need && Snext < (unsigned)need) {
            sh_prefix = (prefix << 8) | (unsigned)t;
            sh_need = need - (int)Snext;
        }
        __syncthreads();
        prefix = sh_prefix;
        need = sh_need;
        __syncthreads();
    }
    const unsigned T = prefix;
    const int need_eq = need;
    const unsigned ngt = (unsigned)(CAPk - need_eq);

    int myeq = 0;
#pragma unroll
    for (int i = 0; i < 16; ++i) myeq += (vu[i] == T) ? 1 : 0;
    // exclusive prefix over thread order
    unsigned e = (unsigned)myeq;
#pragma unroll
    for (int d = 1; d < 64; d <<= 1) {
        unsigned o = __shfl_up(e, d);
        if (lane >= d) e += o;
    }
    if (lane == 63) wtot[w] = e;
    if (t == 0) cnt_gt = 0;
    __syncthreads();
    unsigned eqr = e - (unsigned)myeq;
#pragma unroll
    for (int w2 = 0; w2 < 4; ++w2)
        if (w2 < w) eqr += wtot[w2];
#pragma unroll
    for (int i = 0; i < 16; ++i) {
        unsigned u = vu[i];
        int s = t * 16 + i;
        if (u > T) {
            unsigned slot = atomicAdd(&cnt_gt, 1u);
            sel_idx[(size_t)be * CAPk + slot] = s;
            sel_gate[(size_t)be * CAPk + slot] = __uint_as_float(u);
        } else if (u == T) {
            if ((int)eqr < need_eq) {
                unsigned slot = ngt + eqr;
                sel_idx[(size_t)be * CAPk + slot] = s;
                sel_gate[(size_t)be * CAPk + slot] = __uint_as_float(u);
            }
            eqr++;
        }
    }
}

__global__ void zero2_kernel(float* __restrict__ sums, int* __restrict__ cnt) {
    int i = blockIdx.x * 256 + threadIdx.x;   // grid = 64 blocks -> 16384
    sums[i] = 0.f;
    cnt[i] = 0;
}

__global__ void accum_kernel(const int* __restrict__ sel_idx,
                             const float* __restrict__ sel_gate,
                             float* __restrict__ sums) {
    int g = blockIdx.x * 256 + threadIdx.x;
    int be = g / CAPk;
    int b = be >> 4;
    atomicAdd(&sums[b * Ss + sel_idx[g]], sel_gate[g]);
}

// also builds the token->slot inverse map for the fused combine
__global__ void finalize_kernel(const int* __restrict__ sel_idx,
                                const float* __restrict__ sel_gate,
                                const float* __restrict__ sums,
                                int* __restrict__ slot_token,
                                float* __restrict__ slot_w,
                                int* __restrict__ cnt,
                                int* __restrict__ inv) {
    int g = blockIdx.x * 256 + threadIdx.x;
    int be = g / CAPk, c = g % CAPk;
    int b = be >> 4, e = be & 15;
    int token = b * Ss + sel_idx[g];
    float wv = sel_gate[g] / (sums[token] + 1e-12f);
    int o = (e * Bb + b) * CAPk + c;
    slot_token[o] = token;
    slot_w[o] = wv;
    int pos = atomicAdd(&cnt[token], 1);
    inv[(size_t)token * 16 + pos] = o;
}

// ---------------- conversion / transpose / gather ----------------

__global__ __launch_bounds__(256)
void convert_bf16(const float* __restrict__ src, u16* __restrict__ dst) {
    int i = (blockIdx.x * 256 + threadIdx.x) * 4;
    float4 v = *(const float4*)(src + i);
    ushort4v o = { f2b(v.x), f2b(v.y), f2b(v.z), f2b(v.w) };
    *(ushort4v*)(dst + i) = o;
}

// 64x64 tile fp32 [K][N] -> bf16 [N][K] (K total = 1024), float4 loads + short8 stores
__global__ __launch_bounds__(256)
void transpose_bf16(const float* __restrict__ W, u16* __restrict__ Wt,
                    int N, size_t zsrc, size_t zdst) {
    __shared__ float tile[64][65];
    int n0 = blockIdx.x * 64, k0 = blockIdx.y * 64, z = blockIdx.z;
    const float* Ws = W + (size_t)z * zsrc;
    u16* Wd = Wt + (size_t)z * zdst;
    int t = threadIdx.x;
    int lr = t >> 4, lc = (t & 15) * 4;   // 16 rows/round x 16 float4 cols
#pragma unroll
    for (int i = 0; i < 4; ++i) {
        float4 v = *(const float4*)&Ws[(size_t)(k0 + lr + i * 16) * N + n0 + lc];
        tile[lr + i * 16][lc + 0] = v.x;
        tile[lr + i * 16][lc + 1] = v.y;
        tile[lr + i * 16][lc + 2] = v.z;
        tile[lr + i * 16][lc + 3] = v.w;
    }
    __syncthreads();
    int on = t >> 2;            // output n row 0..63
    int ok0 = (t & 3) * 16;     // 16 k elems per thread
    u16 buf[16];
#pragma unroll
    for (int j = 0; j < 16; ++j) buf[j] = f2b(tile[ok0 + j][on]);
    u16* dp = &Wd[(size_t)(n0 + on) * 1024 + k0 + ok0];
    *(short8*)(dp) = *(short8*)&buf[0];
    *(short8*)(dp + 8) = *(short8*)&buf[8];
}

__global__ __launch_bounds__(256)
void gather_bf16(const float* __restrict__ X, const int* __restrict__ slot_token,
                 u16* __restrict__ Ag, int e0) {
    int z = blockIdx.x >> 11, li = blockIdx.x & 2047;
    int token = slot_token[(e0 + z) * 2048 + li];
    const float* src = X + (size_t)token * 1024;
    u16* dst = Ag + (size_t)blockIdx.x * 1024;
    int i = threadIdx.x * 4;
    float4 v = *(const float4*)(src + i);
    ushort4v o = { f2b(v.x), f2b(v.y), f2b(v.z), f2b(v.w) };
    *(ushort4v*)(dst + i) = o;
}

// ---------------- MFMA GEMMs (m97-style: 128x128 tile, BK=64, global_load_lds, XOR swizzle) ----------------

__device__ __forceinline__ void stage_tile(const u16* __restrict__ grow, int k0,
                                           u16* lds, int t) {
#pragma unroll
    for (int r = 0; r < 4; ++r) {
        int o = (r * 256 + t) * 16;            // byte offset in 16KB tile
        int m = o >> 7;                        // row 0..127
        int c = ((o >> 4) & 7) ^ (m & 7);      // global 16B chunk
        const u16* src = grow + (size_t)m * 1024 + k0 + c * 8;
        u16* dst = lds + ((r * 4096 + (t >> 6) * 1024) >> 1);  // wave-uniform
        gl_lds16(src, dst);
    }
}

template <bool SILU_FIRST>
__global__ __launch_bounds__(256, 2)
void gemm1_mfma(const u16* __restrict__ A, int a_row0, int zstride,
                const u16* __restrict__ W1t, u16* __restrict__ act) {
    __shared__ u16 lA[128 * 64];
    __shared__ u16 lB1[128 * 64];
    __shared__ u16 lB2[128 * 64];
    const int t = threadIdx.x;
    const int n0 = blockIdx.x * 128;
    const int bm0 = blockIdx.y * 128;
    const int z = blockIdx.z;
    const int zb = z * zstride;
    const u16* Arow = A + (size_t)(a_row0 + zb + bm0) * 1024;
    const u16* B1row = W1t + ((size_t)z * 2048 + n0) * 1024;
    const u16* B2row = B1row + (size_t)1024 * 1024;
    const int lane = t & 63;
    const int wv = t >> 6, wm = wv & 1, wn = wv >> 1;
    const int quad = lane >> 4, l15 = lane & 15;

    floatx4 zero4 = {0.f, 0.f, 0.f, 0.f};
    floatx4 acc1[4][4], acc2[4][4];
#pragma unroll
    for (int i = 0; i < 4; ++i)
#pragma unroll
        for (int j = 0; j < 4; ++j) { acc1[i][j] = zero4; acc2[i][j] = zero4; }

    for (int k0 = 0; k0 < 1024; k0 += 64) {
        __syncthreads();
        stage_tile(Arow, k0, lA, t);
        stage_tile(B1row, k0, lB1, t);
        stage_tile(B2row, k0, lB2, t);
        __syncthreads();
#pragma unroll
        for (int kc = 0; kc < 2; ++kc) {
            short8 af[4], bf1[4], bf2[4];
#pragma unroll
            for (int mi = 0; mi < 4; ++mi) {
                int m = wm * 64 + mi * 16 + l15;
                int off = m * 64 + (((kc * 4 + quad) ^ (m & 7)) * 8);
                af[mi] = *(const short8*)&lA[off];
            }
#pragma unroll
            for (int ni = 0; ni < 4; ++ni) {
                int n = wn * 64 + ni * 16 + l15;
                int off = n * 64 + (((kc * 4 + quad) ^ (n & 7)) * 8);
                bf1[ni] = *(const short8*)&lB1[off];
                bf2[ni] = *(const short8*)&lB2[off];
            }
#pragma unroll
            for (int mi = 0; mi < 4; ++mi)
#pragma unroll
                for (int ni = 0; ni < 4; ++ni) {
                    acc1[mi][ni] = __builtin_amdgcn_mfma_f32_16x16x32_bf16(af[mi], bf1[ni], acc1[mi][ni], 0, 0, 0);
                    acc2[mi][ni] = __builtin_amdgcn_mfma_f32_16x16x32_bf16(af[mi], bf2[ni], acc2[mi][ni], 0, 0, 0);
                }
        }
    }
#pragma unroll
    for (int mi = 0; mi < 4; ++mi)
#pragma unroll
        for (int ni = 0; ni < 4; ++ni)
#pragma unroll
            for (int r = 0; r < 4; ++r) {
                int m = wm * 64 + mi * 16 + quad * 4 + r;
                int n = wn * 64 + ni * 16 + l15;
                float c1 = acc1[mi][ni][r], c2 = acc2[mi][ni][r];
                float v = SILU_FIRST ? silu_f(c1) * c2 : c1 * silu_f(c2);
                act[(size_t)(zb + bm0 + m) * 1024 + n0 + n] = f2b(v);
            }
}

// MODE: 0 = plain store, 1 = atomic scatter (legacy), 2 = weighted eo write,
//       3 = plain store + fused combine (out = c + sum of eo slot rows)
template <int MODE>
__global__ __launch_bounds__(256, 2)
void gemm2_mfma(const u16* __restrict__ A, int zstride,
                const u16* __restrict__ W2t,
                const int* __restrict__ slot_token, const float* __restrict__ slot_w,
                float* __restrict__ out, int out_row0, int e_base,
                const int* __restrict__ cnt, const int* __restrict__ inv,
                const float* __restrict__ eo) {
    __shared__ u16 lA[128 * 64];
    __shared__ u16 lB[128 * 64];
    __shared__ int s_tok[(MODE == 1) ? 128 : 1];
    __shared__ float s_w[(MODE == 1 || MODE == 2) ? 128 : 1];
    __shared__ int s_cnt[(MODE == 3) ? 128 : 1];
    __shared__ int s_inv[(MODE == 3) ? 128 * 16 : 1];
    const int t = threadIdx.x;
    const int n0 = blockIdx.x * 128;
    const int bm0 = blockIdx.y * 128;
    const int z = blockIdx.z;
    const int zb = z * zstride;
    const u16* Arow = A + (size_t)(zb + bm0) * 1024;
    const u16* Brow = W2t + ((size_t)z * 1024 + n0) * 1024;
    const int lane = t & 63;
    const int wv = t >> 6, wm = wv & 1, wn = wv >> 1;
    const int quad = lane >> 4, l15 = lane & 15;

    if ((MODE == 1 || MODE == 2) && t < 128) {
        int gi = (e_base + z) * 2048 + bm0 + t;
        if (MODE == 1) s_tok[t] = slot_token[gi];
        s_w[t] = slot_w[gi];
    }
    if (MODE == 3) {
        int base = out_row0 + bm0;
        if (t < 128) s_cnt[t] = cnt[base + t];
        for (int j = t; j < 128 * 16; j += 256) s_inv[j] = inv[(size_t)base * 16 + j];
    }

    floatx4 zero4 = {0.f, 0.f, 0.f, 0.f};
    floatx4 acc[4][4];
#pragma unroll
    for (int i = 0; i < 4; ++i)
#pragma unroll
        for (int j = 0; j < 4; ++j) acc[i][j] = zero4;

    for (int k0 = 0; k0 < 1024; k0 += 64) {
        __syncthreads();
        stage_tile(Arow, k0, lA, t);
        stage_tile(Brow, k0, lB, t);
        __syncthreads();
#pragma unroll
        for (int kc = 0; kc < 2; ++kc) {
            short8 af[4], bf[4];
#pragma unroll
            for (int mi = 0; mi < 4; ++mi) {
                int m = wm * 64 + mi * 16 + l15;
                int off = m * 64 + (((kc * 4 + quad) ^ (m & 7)) * 8);
                af[mi] = *(const short8*)&lA[off];
            }
#pragma unroll
            for (int ni = 0; ni < 4; ++ni) {
                int n = wn * 64 + ni * 16 + l15;
                int off = n * 64 + (((kc * 4 + quad) ^ (n & 7)) * 8);
                bf[ni] = *(const short8*)&lB[off];
            }
#pragma unroll
            for (int mi = 0; mi < 4; ++mi)
#pragma unroll
                for (int ni = 0; ni < 4; ++ni)
                    acc[mi][ni] = __builtin_amdgcn_mfma_f32_16x16x32_bf16(af[mi], bf[ni], acc[mi][ni], 0, 0, 0);
        }
    }
#pragma unroll
    for (int mi = 0; mi < 4; ++mi)
#pragma unroll
        for (int ni = 0; ni < 4; ++ni)
#pragma unroll
            for (int r = 0; r < 4; ++r) {
                int m = wm * 64 + mi * 16 + quad * 4 + r;
                int n = wn * 64 + ni * 16 + l15;
                float c = acc[mi][ni][r];
                if (MODE == 1) {
                    atomicAdd(&out[(size_t)s_tok[m] * 1024 + n0 + n], c * s_w[m]);
                } else if (MODE == 2) {
                    out[((size_t)((e_base + z) * 2048 + bm0 + m)) * 1024 + n0 + n] = c * s_w[m];
                } else if (MODE == 3) {
                    float v = c;
                    int kc2 = s_cnt[m];
                    for (int j = 0; j < kc2; ++j)
                        v += eo[(size_t)s_inv[m * 16 + j] * 1024 + n0 + n];
                    out[(size_t)(out_row0 + bm0 + m) * 1024 + n0 + n] = v;
                } else {
                    out[(size_t)(out_row0 + bm0 + m) * 1024 + n0 + n] = c;
                }
            }
}

// ---------------- host launcher ----------------

extern "C" void kernel_launch(void* const* d_in, const int* in_sizes, int n_in,
                              void* d_out, int out_size, void* d_ws, size_t ws_size,
                              hipStream_t stream) {
    const float* hidden   = (const float*)d_in[0];
    const float* hsu      = (const float*)d_in[1];
    const float* timestep = (const float*)d_in[2];
    const float* gate_w   = (const float*)d_in[3];
    const float* gate_up  = (const float*)d_in[4];
    const float* down     = (const float*)d_in[5];
    const float* sh_gu    = (const float*)d_in[6];
    const float* sh_dn    = (const float*)d_in[7];
    float* out = (float*)d_out;

    char* p = (char*)d_ws;
    auto alloc = [&](size_t bytes) { char* r = p; p += (bytes + 255) & ~(size_t)255; return r; };
    float* scores    = (float*)alloc((size_t)Bb * Ee * Ss * 4);
    int*   sel_idx   = (int*)  alloc((size_t)Bb * Ee * CAPk * 4);
    float* sel_gate  = (float*)alloc((size_t)Bb * Ee * CAPk * 4);
    float* sums      = (float*)alloc((size_t)Bb * Ss * 4);
    int*   slot_token= (int*)  alloc((size_t)Ee * Bb * CAPk * 4);
    float* slot_w    = (float*)alloc((size_t)Ee * Bb * CAPk * 4);
    int*   cnt       = (int*)  alloc((size_t)Bb * Ss * 4);
    int*   inv       = (int*)  alloc((size_t)Bb * Ss * 16 * 4);
    char* phase = p;
    long long avail = (long long)((char*)d_ws + ws_size - phase);
    if (avail < 0) avail = 0;

    const long long eo_bytes     = (long long)32768 * 1024 * 4;                       // 134 MB
    const long long shared_fixed = ((long long)16384 * 1024 + 2048 * 1024 + 1024 * 1024) * 2;
    const long long per_e        = ((long long)2048 * 1024 * 3 + 1024 * 1024) * 2;    // 14 MB

    // --- router ---
    router_scores<<<(Bb * Ss) / 64, 256, 0, stream>>>(hsu, gate_w, timestep, scores);
    topk_kernel<<<Bb * Ee, 256, 0, stream>>>(scores, sel_idx, sel_gate);
    zero2_kernel<<<(Bb * Ss) / 256, 256, 0, stream>>>(sums, cnt);
    accum_kernel<<<(Bb * Ee * CAPk) / 256, 256, 0, stream>>>(sel_idx, sel_gate, sums);
    finalize_kernel<<<(Bb * Ee * CAPk) / 256, 256, 0, stream>>>(sel_idx, sel_gate, sums,
                                                                slot_token, slot_w, cnt, inv);

    bool use_eo = (avail >= eo_bytes + shared_fixed + (long long)128 * 2048) &&
                  (avail - eo_bytes >= per_e);

    if (use_eo) {
        float* eo = (float*)phase;
        char* ph2 = phase + eo_bytes;
        long long avail2 = avail - eo_bytes;

        // --- routed experts first: gemm2 writes weighted rows to dense eo (no atomics) ---
        {
            int g = (int)(avail2 / per_e);
            if (g < 1) g = 1;
            if (g > Ee) g = Ee;
            u16* Ag   = (u16*)ph2;
            u16* Wt1r = Ag   + (size_t)g * 2048 * 1024;
            u16* Wt2r = Wt1r + (size_t)g * 2048 * 1024;
            u16* actR = Wt2r + (size_t)g * 1024 * 1024;

            for (int e0 = 0; e0 < Ee; e0 += g) {
                int cg = Ee - e0; if (cg > g) cg = g;
                gather_bf16<<<cg * 2048, 256, 0, stream>>>(hidden, slot_token, Ag, e0);
                transpose_bf16<<<dim3(32, 16, cg), 256, 0, stream>>>(
                    gate_up + (size_t)e0 * 2097152, Wt1r, 2048, 2097152, 2097152);
                transpose_bf16<<<dim3(16, 16, cg), 256, 0, stream>>>(
                    down + (size_t)e0 * 1048576, Wt2r, 1024, 1048576, 1048576);
                gemm1_mfma<true><<<dim3(8, 16, cg), 256, 0, stream>>>(Ag, 0, 2048, Wt1r, actR);
                gemm2_mfma<2><<<dim3(8, 16, cg), 256, 0, stream>>>(actR, 2048, Wt2r,
                                                                   slot_token, slot_w, eo, 0, e0,
                                                                   nullptr, nullptr, nullptr);
            }
        }

        // --- shared expert phase: gemm2 epilogue fuses the routed combine ---
        {
            u16* Xb   = (u16*)ph2;
            u16* Wt1s = Xb + (size_t)16384 * 1024;
            u16* Wt2s = Wt1s + (size_t)2048 * 1024;
            u16* actS = Wt2s + (size_t)1024 * 1024;
            long long room = (avail2 - shared_fixed) / 2048;   // act rows
            room &= ~127LL;
            int R = (int)(room > 16384 ? 16384 : room);
            if (R < 128) R = 128;

            convert_bf16<<<16384, 256, 0, stream>>>(hidden, Xb);
            transpose_bf16<<<dim3(32, 16, 1), 256, 0, stream>>>(sh_gu, Wt1s, 2048, 0, 0);
            transpose_bf16<<<dim3(16, 16, 1), 256, 0, stream>>>(sh_dn, Wt2s, 1024, 0, 0);
            for (int r0 = 0; r0 < Bb * Ss; r0 += R) {
                int cur = Bb * Ss - r0; if (cur > R) cur = R;
                gemm1_mfma<false><<<dim3(8, cur / 128, 1), 256, 0, stream>>>(Xb, r0, 0, Wt1s, actS);
                gemm2_mfma<3><<<dim3(8, cur / 128, 1), 256, 0, stream>>>(actS, 0, Wt2s,
                                                                         nullptr, nullptr, out, r0, 0,
                                                                         cnt, inv, eo);
            }
        }
    } else {
        // --- legacy fallback: shared phase writes out, routed scatters atomically ---
        {
            u16* Xb   = (u16*)phase;
            u16* Wt1s = Xb + (size_t)16384 * 1024;
            u16* Wt2s = Wt1s + (size_t)2048 * 1024;
            u16* actS = Wt2s + (size_t)1024 * 1024;
            long long room = (avail - shared_fixed) / 2048;
            room &= ~127LL;
            int R = (int)(room > 16384 ? 16384 : room);
            if (R < 128) R = 128;

            convert_bf16<<<16384, 256, 0, stream>>>(hidden, Xb);
            transpose_bf16<<<dim3(32, 16, 1), 256, 0, stream>>>(sh_gu, Wt1s, 2048, 0, 0);
            transpose_bf16<<<dim3(16, 16, 1), 256, 0, stream>>>(sh_dn, Wt2s, 1024, 0, 0);
            for (int r0 = 0; r0 < Bb * Ss; r0 += R) {
                int cur = Bb * Ss - r0; if (cur > R) cur = R;
                gemm1_mfma<false><<<dim3(8, cur / 128, 1), 256, 0, stream>>>(Xb, r0, 0, Wt1s, actS);
                gemm2_mfma<0><<<dim3(8, cur / 128, 1), 256, 0, stream>>>(actS, 0, Wt2s,
                                                                         nullptr, nullptr, out, r0, 0,
                                                                         nullptr, nullptr, nullptr);
            }
        }
        {
            int g = (int)(avail / per_e);
            if (g < 1) g = 1;
            if (g > Ee) g = Ee;
            u16* Ag   = (u16*)phase;
            u16* Wt1r = Ag   + (size_t)g * 2048 * 1024;
            u16* Wt2r = Wt1r + (size_t)g * 2048 * 1024;
            u16* actR = Wt2r + (size_t)g * 1024 * 1024;

            for (int e0 = 0; e0 < Ee; e0 += g) {
                int cg = Ee - e0; if (cg > g) cg = g;
                gather_bf16<<<cg * 2048, 256, 0, stream>>>(hidden, slot_token, Ag, e0);
                transpose_bf16<<<dim3(32, 16, cg), 256, 0, stream>>>(
                    gate_up + (size_t)e0 * 2097152, Wt1r, 2048, 2097152, 2097152);
                transpose_bf16<<<dim3(16, 16, cg), 256, 0, stream>>>(
                    down + (size_t)e0 * 1048576, Wt2r, 1024, 1048576, 1048576);
                gemm1_mfma<true><<<dim3(8, 16, cg), 256, 0, stream>>>(Ag, 0, 2048, Wt1r, actR);
                gemm2_mfma<1><<<dim3(8, 16, cg), 256, 0, stream>>>(actR, 2048, Wt2r,
                                                                   slot_token, slot_w, out, 0, e0,
                                                                   nullptr, nullptr, nullptr);
            }
        }
    }
}

// Round 2
// 803.300 us; speedup vs baseline: 1.2653x; 1.2653x over previous
//
#include <hip/hip_runtime.h>
#include <math.h>

// Problem constants
#define Bb 4
#define Ss 4096
#define Hh 1024
#define Mm 1024
#define Ee 16
#define CAPk 512            // ceil(2.0 * 4096 / 16)

typedef unsigned short u16;
typedef __attribute__((ext_vector_type(8))) short short8;
typedef __attribute__((ext_vector_type(4))) float floatx4;
typedef __attribute__((ext_vector_type(4))) unsigned short ushort4v;

__device__ __forceinline__ float silu_f(float x) {
    return x / (1.0f + expf(-x));
}

// fp32 -> bf16 (RNE)
__device__ __forceinline__ u16 f2b(float x) {
    union { float f; unsigned u; } v; v.f = x;
    unsigned r = (v.u + 0x7fffu + ((v.u >> 16) & 1u)) >> 16;
    return (u16)r;
}

// async 16B global->LDS (wave-uniform LDS base + lane*16)
__device__ __forceinline__ void gl_lds16(const void* g, void* l) {
    __builtin_amdgcn_global_load_lds((const __attribute__((address_space(1))) void*)g,
                                     (__attribute__((address_space(3))) void*)l, 16, 0, 0);
}

// ---------------- router ----------------

// Skinny GEMM: scores[b,e,s] = sigmoid(tlogit[b,e] + hsu[token,:] . gw2[:,e])
// tlogit (timestep . gate_w first half) computed inline per wave (4 experts).
__global__ __launch_bounds__(256)
void router_scores(const float* __restrict__ hsu,
                   const float* __restrict__ gate_w,
                   const float* __restrict__ timestep,
                   float* __restrict__ scores) {
    __shared__ float Xs[64 * 64];   // 16 KB, swizzled 16B chunks
    __shared__ float Gs[64 * 16];   // 4 KB
    const int t = threadIdx.x;
    const int row0 = blockIdx.x * 64;        // token base (never crosses b: 4096%64==0)
    const int b = row0 >> 12;
    const int wave = t >> 6, lane = t & 63;
    const int e0 = wave * 4;
    const float* gw2 = gate_w + (size_t)Hh * Ee;   // [k][16] second-half rows

    // inline tlogit for this wave's 4 experts
    float tl0 = 0.f, tl1 = 0.f, tl2 = 0.f, tl3 = 0.f;
    {
        const float* tsrow = timestep + (size_t)b * Hh;
#pragma unroll
        for (int j = 0; j < 16; ++j) {
            int h = lane + 64 * j;
            float tv = tsrow[h];
            const float* gw = gate_w + (size_t)h * Ee + e0;
            tl0 += tv * gw[0]; tl1 += tv * gw[1]; tl2 += tv * gw[2]; tl3 += tv * gw[3];
        }
#pragma unroll
        for (int off = 32; off; off >>= 1) {
            tl0 += __shfl_xor(tl0, off); tl1 += __shfl_xor(tl1, off);
            tl2 += __shfl_xor(tl2, off); tl3 += __shfl_xor(tl3, off);
        }
    }

    float acc0 = 0.f, acc1 = 0.f, acc2 = 0.f, acc3 = 0.f;

    for (int k0 = 0; k0 < Hh; k0 += 64) {
        __syncthreads();
#pragma unroll
        for (int r = 0; r < 4; ++r) {
            int tok = r * 16 + (t >> 4);
            int cslot = t & 15;                 // dest 16B slot within row
            int g = cslot ^ (tok & 15);         // source chunk (swizzle via source)
            const float* src = hsu + (size_t)(row0 + tok) * Hh + k0 + g * 4;
            char* dst = (char*)Xs + r * 4096 + wave * 1024;   // wave-uniform
            gl_lds16(src, dst);
        }
        {
            const float* src = gw2 + (size_t)k0 * Ee + t * 4;
            char* dst = (char*)Gs + wave * 1024;
            gl_lds16(src, dst);
        }
        __syncthreads();
#pragma unroll
        for (int kk = 0; kk < 64; kk += 4) {
            int slot = (kk >> 2) ^ (lane & 15);
            float4 a = *(const float4*)&Xs[lane * 64 + slot * 4];
            float4 g0 = *(const float4*)&Gs[(kk + 0) * Ee + e0];
            float4 g1 = *(const float4*)&Gs[(kk + 1) * Ee + e0];
            float4 g2 = *(const float4*)&Gs[(kk + 2) * Ee + e0];
            float4 g3 = *(const float4*)&Gs[(kk + 3) * Ee + e0];
            acc0 += a.x * g0.x; acc0 += a.y * g1.x; acc0 += a.z * g2.x; acc0 += a.w * g3.x;
            acc1 += a.x * g0.y; acc1 += a.y * g1.y; acc1 += a.z * g2.y; acc1 += a.w * g3.y;
            acc2 += a.x * g0.z; acc2 += a.y * g1.z; acc2 += a.z * g2.z; acc2 += a.w * g3.z;
            acc3 += a.x * g0.w; acc3 += a.y * g1.w; acc3 += a.z * g2.w; acc3 += a.w * g3.w;
        }
    }
    const int s = (row0 + lane) & (Ss - 1);
    float l0 = acc0 + tl0;
    float l1 = acc1 + tl1;
    float l2 = acc2 + tl2;
    float l3 = acc3 + tl3;
    scores[((size_t)(b * Ee + e0 + 0)) * Ss + s] = 1.f / (1.f + expf(-l0));
    scores[((size_t)(b * Ee + e0 + 1)) * Ss + s] = 1.f / (1.f + expf(-l1));
    scores[((size_t)(b * Ee + e0 + 2)) * Ss + s] = 1.f / (1.f + expf(-l2));
    scores[((size_t)(b * Ee + e0 + 3)) * Ss + s] = 1.f / (1.f + expf(-l3));
}

// Radix top-k with wave-parallel suffix scans (no serial t0 loops).
__global__ __launch_bounds__(256)
void topk_kernel(const float* __restrict__ scores,
                 int* __restrict__ sel_idx,
                 float* __restrict__ sel_gate) {
    const int be = blockIdx.x;
    const float* sc = scores + (size_t)be * Ss;
    const int t = threadIdx.x;
    const int lane = t & 63, w = t >> 6;
    __shared__ unsigned hist[256];
    __shared__ unsigned wtot[4];
    __shared__ unsigned sh_prefix;
    __shared__ int sh_need;
    __shared__ unsigned cnt_gt;

    unsigned vu[16];
#pragma unroll
    for (int i = 0; i < 16; ++i) vu[i] = __float_as_uint(sc[t * 16 + i]);

    unsigned prefix = 0;
    int need = CAPk;
    for (int pass = 0; pass < 4; ++pass) {
        const int shift = 24 - 8 * pass;
        hist[t] = 0;
        __syncthreads();
#pragma unroll
        for (int i = 0; i < 16; ++i) {
            unsigned u = vu[i];
            bool ok = (pass == 0) || ((u >> (shift + 8)) == prefix);
            if (ok) atomicAdd(&hist[(u >> shift) & 255u], 1u);
        }
        __syncthreads();
        unsigned hval = hist[t];
        unsigned s = hval;
        // intra-wave inclusive suffix scan (bin t covers [t .. wave_end])
#pragma unroll
        for (int d = 1; d < 64; d <<= 1) {
            unsigned o = __shfl_down(s, d);
            if (lane + d < 64) s += o;
        }
        if (lane == 0) wtot[w] = s;   // wave total
        __syncthreads();
#pragma unroll
        for (int w2 = 0; w2 < 4; ++w2)
            if (w2 > w) s += wtot[w2];
        // s = S[t] = sum_{j>=t} hist[j]; exactly one t satisfies the bracket
        unsigned Snext = s - hval;
        if (s >= (unsigned)need && Snext < (unsigned)need) {
            sh_prefix = (prefix << 8) | (unsigned)t;
            sh_need = need - (int)Snext;
        }
        __syncthreads();
        prefix = sh_prefix;
        need = sh_need;
        __syncthreads();
    }
    const unsigned T = prefix;
    const int need_eq = need;
    const unsigned ngt = (unsigned)(CAPk - need_eq);

    int myeq = 0;
#pragma unroll
    for (int i = 0; i < 16; ++i) myeq += (vu[i] == T) ? 1 : 0;
    // exclusive prefix over thread order
    unsigned e = (unsigned)myeq;
#pragma unroll
    for (int d = 1; d < 64; d <<= 1) {
        unsigned o = __shfl_up(e, d);
        if (lane >= d) e += o;
    }
    if (lane == 63) wtot[w] = e;
    if (t == 0) cnt_gt = 0;
    __syncthreads();
    unsigned eqr = e - (unsigned)myeq;
#pragma unroll
    for (int w2 = 0; w2 < 4; ++w2)
        if (w2 < w) eqr += wtot[w2];
#pragma unroll
    for (int i = 0; i < 16; ++i) {
        unsigned u = vu[i];
        int s = t * 16 + i;
        if (u > T) {
            unsigned slot = atomicAdd(&cnt_gt, 1u);
            sel_idx[(size_t)be * CAPk + slot] = s;
            sel_gate[(size_t)be * CAPk + slot] = __uint_as_float(u);
        } else if (u == T) {
            if ((int)eqr < need_eq) {
                unsigned slot = ngt + eqr;
                sel_idx[(size_t)be * CAPk + slot] = s;
                sel_gate[(size_t)be * CAPk + slot] = __uint_as_float(u);
            }
            eqr++;
        }
    }
}

__global__ void zero2_kernel(float* __restrict__ sums, int* __restrict__ cnt) {
    int i = blockIdx.x * 256 + threadIdx.x;   // grid = 64 blocks -> 16384
    sums[i] = 0.f;
    cnt[i] = 0;
}

__global__ void accum_kernel(const int* __restrict__ sel_idx,
                             const float* __restrict__ sel_gate,
                             float* __restrict__ sums) {
    int g = blockIdx.x * 256 + threadIdx.x;
    int be = g / CAPk;
    int b = be >> 4;
    atomicAdd(&sums[b * Ss + sel_idx[g]], sel_gate[g]);
}

// also builds the token->slot inverse map for the dense combine
__global__ void finalize_kernel(const int* __restrict__ sel_idx,
                                const float* __restrict__ sel_gate,
                                const float* __restrict__ sums,
                                int* __restrict__ slot_token,
                                float* __restrict__ slot_w,
                                int* __restrict__ cnt,
                                int* __restrict__ inv) {
    int g = blockIdx.x * 256 + threadIdx.x;
    int be = g / CAPk, c = g % CAPk;
    int b = be >> 4, e = be & 15;
    int token = b * Ss + sel_idx[g];
    float wv = sel_gate[g] / (sums[token] + 1e-12f);
    int o = (e * Bb + b) * CAPk + c;
    slot_token[o] = token;
    slot_w[o] = wv;
    int pos = atomicAdd(&cnt[token], 1);
    inv[(size_t)token * 16 + pos] = o;
}

// dedicated high-occupancy combine: out[token] += sum_j eo[slot_j]
__global__ __launch_bounds__(256)
void combine_kernel(const int* __restrict__ cnt, const int* __restrict__ inv,
                    const float* __restrict__ eo, float* __restrict__ out) {
    const int token = blockIdx.x;           // 16384
    const int k = cnt[token];               // wave-uniform scalar
    if (k == 0) return;
    const int col = threadIdx.x * 4;
    const size_t rowoff = (size_t)token * 1024 + col;
    float4 acc = *(const float4*)(out + rowoff);
    for (int j = 0; j < k; ++j) {
        int slot = inv[token * 16 + j];     // wave-uniform
        float4 v = *(const float4*)(eo + (size_t)slot * 1024 + col);
        acc.x += v.x; acc.y += v.y; acc.z += v.z; acc.w += v.w;
    }
    *(float4*)(out + rowoff) = acc;
}

// ---------------- conversion / transpose ----------------

__global__ __launch_bounds__(256)
void convert_bf16(const float* __restrict__ src, u16* __restrict__ dst) {
    int i = (blockIdx.x * 256 + threadIdx.x) * 4;
    float4 v = *(const float4*)(src + i);
    ushort4v o = { f2b(v.x), f2b(v.y), f2b(v.z), f2b(v.w) };
    *(ushort4v*)(dst + i) = o;
}

// 64x64 tile fp32 [K][N] -> bf16 [N][K] (K total = 1024), float4 loads + short8 stores
__global__ __launch_bounds__(256)
void transpose_bf16(const float* __restrict__ W, u16* __restrict__ Wt,
                    int N, size_t zsrc, size_t zdst) {
    __shared__ float tile[64][65];
    int n0 = blockIdx.x * 64, k0 = blockIdx.y * 64, z = blockIdx.z;
    const float* Ws = W + (size_t)z * zsrc;
    u16* Wd = Wt + (size_t)z * zdst;
    int t = threadIdx.x;
    int lr = t >> 4, lc = (t & 15) * 4;   // 16 rows/round x 16 float4 cols
#pragma unroll
    for (int i = 0; i < 4; ++i) {
        float4 v = *(const float4*)&Ws[(size_t)(k0 + lr + i * 16) * N + n0 + lc];
        tile[lr + i * 16][lc + 0] = v.x;
        tile[lr + i * 16][lc + 1] = v.y;
        tile[lr + i * 16][lc + 2] = v.z;
        tile[lr + i * 16][lc + 3] = v.w;
    }
    __syncthreads();
    int on = t >> 2;            // output n row 0..63
    int ok0 = (t & 3) * 16;     // 16 k elems per thread
    u16 buf[16];
#pragma unroll
    for (int j = 0; j < 16; ++j) buf[j] = f2b(tile[ok0 + j][on]);
    u16* dp = &Wd[(size_t)(n0 + on) * 1024 + k0 + ok0];
    *(short8*)(dp) = *(short8*)&buf[0];
    *(short8*)(dp + 8) = *(short8*)&buf[8];
}

// ---------------- MFMA GEMMs (m97-style: 128x128 tile, BK=64, global_load_lds, XOR swizzle) ----------------

__device__ __forceinline__ void stage_tile(const u16* __restrict__ grow, int k0,
                                           u16* lds, int t) {
#pragma unroll
    for (int r = 0; r < 4; ++r) {
        int o = (r * 256 + t) * 16;            // byte offset in 16KB tile
        int m = o >> 7;                        // row 0..127
        int c = ((o >> 4) & 7) ^ (m & 7);      // global 16B chunk
        const u16* src = grow + (size_t)m * 1024 + k0 + c * 8;
        u16* dst = lds + ((r * 4096 + (t >> 6) * 1024) >> 1);  // wave-uniform
        gl_lds16(src, dst);
    }
}

// A-stage with per-row indirection (row ids precomputed per thread)
__device__ __forceinline__ void stage_rows(const u16* __restrict__ A, const int* rid,
                                           int k0, u16* lds, int t) {
#pragma unroll
    for (int r = 0; r < 4; ++r) {
        int m = (t >> 3) + 32 * r;             // row within tile 0..127
        int c = (t & 7) ^ (m & 7);             // swizzled 16B chunk
        const u16* src = A + (size_t)rid[r] * 1024 + k0 + c * 8;
        u16* dst = lds + ((r * 4096 + (t >> 6) * 1024) >> 1);  // wave-uniform
        gl_lds16(src, dst);
    }
}

template <bool SILU_FIRST, bool GATHER>
__global__ __launch_bounds__(256, 2)
void gemm1_mfma(const u16* __restrict__ A, int a_row0, int zstride,
                const u16* __restrict__ W1t, u16* __restrict__ act,
                const int* __restrict__ slot_token, int e_base) {
    __shared__ u16 lA[128 * 64];
    __shared__ u16 lB1[128 * 64];
    __shared__ u16 lB2[128 * 64];
    const int t = threadIdx.x;
    const int n0 = blockIdx.x * 128;
    const int bm0 = blockIdx.y * 128;
    const int z = blockIdx.z;
    const int zb = z * zstride;
    const u16* B1row = W1t + ((size_t)z * 2048 + n0) * 1024;
    const u16* B2row = B1row + (size_t)1024 * 1024;
    const int lane = t & 63;
    const int wv = t >> 6, wm = wv & 1, wn = wv >> 1;
    const int quad = lane >> 4, l15 = lane & 15;

    // per-thread A row ids (loop-invariant over K)
    int rid[4];
#pragma unroll
    for (int r = 0; r < 4; ++r) {
        int m = (t >> 3) + 32 * r;
        rid[r] = GATHER ? slot_token[(e_base + z) * (Bb * CAPk) + bm0 + m]
                        : (a_row0 + zb + bm0 + m);
    }

    floatx4 zero4 = {0.f, 0.f, 0.f, 0.f};
    floatx4 acc1[4][4], acc2[4][4];
#pragma unroll
    for (int i = 0; i < 4; ++i)
#pragma unroll
        for (int j = 0; j < 4; ++j) { acc1[i][j] = zero4; acc2[i][j] = zero4; }

    for (int k0 = 0; k0 < 1024; k0 += 64) {
        __syncthreads();
        stage_rows(A, rid, k0, lA, t);
        stage_tile(B1row, k0, lB1, t);
        stage_tile(B2row, k0, lB2, t);
        __syncthreads();
#pragma unroll
        for (int kc = 0; kc < 2; ++kc) {
            short8 af[4], bf1[4], bf2[4];
#pragma unroll
            for (int mi = 0; mi < 4; ++mi) {
                int m = wm * 64 + mi * 16 + l15;
                int off = m * 64 + (((kc * 4 + quad) ^ (m & 7)) * 8);
                af[mi] = *(const short8*)&lA[off];
            }
#pragma unroll
            for (int ni = 0; ni < 4; ++ni) {
                int n = wn * 64 + ni * 16 + l15;
                int off = n * 64 + (((kc * 4 + quad) ^ (n & 7)) * 8);
                bf1[ni] = *(const short8*)&lB1[off];
                bf2[ni] = *(const short8*)&lB2[off];
            }
#pragma unroll
            for (int mi = 0; mi < 4; ++mi)
#pragma unroll
                for (int ni = 0; ni < 4; ++ni) {
                    acc1[mi][ni] = __builtin_amdgcn_mfma_f32_16x16x32_bf16(af[mi], bf1[ni], acc1[mi][ni], 0, 0, 0);
                    acc2[mi][ni] = __builtin_amdgcn_mfma_f32_16x16x32_bf16(af[mi], bf2[ni], acc2[mi][ni], 0, 0, 0);
                }
        }
    }
#pragma unroll
    for (int mi = 0; mi < 4; ++mi)
#pragma unroll
        for (int ni = 0; ni < 4; ++ni)
#pragma unroll
            for (int r = 0; r < 4; ++r) {
                int m = wm * 64 + mi * 16 + quad * 4 + r;
                int n = wn * 64 + ni * 16 + l15;
                float c1 = acc1[mi][ni][r], c2 = acc2[mi][ni][r];
                float v = SILU_FIRST ? silu_f(c1) * c2 : c1 * silu_f(c2);
                act[(size_t)(zb + bm0 + m) * 1024 + n0 + n] = f2b(v);
            }
}

// MODE: 0 = plain store, 1 = atomic scatter (legacy), 2 = weighted dense eo write
template <int MODE>
__global__ __launch_bounds__(256, 2)
void gemm2_mfma(const u16* __restrict__ A, int zstride,
                const u16* __restrict__ W2t,
                const int* __restrict__ slot_token, const float* __restrict__ slot_w,
                float* __restrict__ out, int out_row0, int e_base) {
    __shared__ u16 lA[128 * 64];
    __shared__ u16 lB[128 * 64];
    __shared__ int s_tok[(MODE == 1) ? 128 : 1];
    __shared__ float s_w[(MODE == 1 || MODE == 2) ? 128 : 1];
    const int t = threadIdx.x;
    const int n0 = blockIdx.x * 128;
    const int bm0 = blockIdx.y * 128;
    const int z = blockIdx.z;
    const int zb = z * zstride;
    const u16* Arow = A + (size_t)(zb + bm0) * 1024;
    const u16* Brow = W2t + ((size_t)z * 1024 + n0) * 1024;
    const int lane = t & 63;
    const int wv = t >> 6, wm = wv & 1, wn = wv >> 1;
    const int quad = lane >> 4, l15 = lane & 15;

    if ((MODE == 1 || MODE == 2) && t < 128) {
        int gi = (e_base + z) * (Bb * CAPk) + bm0 + t;
        if (MODE == 1) s_tok[t] = slot_token[gi];
        s_w[t] = slot_w[gi];
    }

    floatx4 zero4 = {0.f, 0.f, 0.f, 0.f};
    floatx4 acc[4][4];
#pragma unroll
    for (int i = 0; i < 4; ++i)
#pragma unroll
        for (int j = 0; j < 4; ++j) acc[i][j] = zero4;

    for (int k0 = 0; k0 < 1024; k0 += 64) {
        __syncthreads();
        stage_tile(Arow, k0, lA, t);
        stage_tile(Brow, k0, lB, t);
        __syncthreads();
#pragma unroll
        for (int kc = 0; kc < 2; ++kc) {
            short8 af[4], bf[4];
#pragma unroll
            for (int mi = 0; mi < 4; ++mi) {
                int m = wm * 64 + mi * 16 + l15;
                int off = m * 64 + (((kc * 4 + quad) ^ (m & 7)) * 8);
                af[mi] = *(const short8*)&lA[off];
            }
#pragma unroll
            for (int ni = 0; ni < 4; ++ni) {
                int n = wn * 64 + ni * 16 + l15;
                int off = n * 64 + (((kc * 4 + quad) ^ (n & 7)) * 8);
                bf[ni] = *(const short8*)&lB[off];
            }
#pragma unroll
            for (int mi = 0; mi < 4; ++mi)
#pragma unroll
                for (int ni = 0; ni < 4; ++ni)
                    acc[mi][ni] = __builtin_amdgcn_mfma_f32_16x16x32_bf16(af[mi], bf[ni], acc[mi][ni], 0, 0, 0);
        }
    }
#pragma unroll
    for (int mi = 0; mi < 4; ++mi)
#pragma unroll
        for (int ni = 0; ni < 4; ++ni)
#pragma unroll
            for (int r = 0; r < 4; ++r) {
                int m = wm * 64 + mi * 16 + quad * 4 + r;
                int n = wn * 64 + ni * 16 + l15;
                float c = acc[mi][ni][r];
                if (MODE == 1) {
                    atomicAdd(&out[(size_t)s_tok[m] * 1024 + n0 + n], c * s_w[m]);
                } else if (MODE == 2) {
                    out[((size_t)((e_base + z) * (Bb * CAPk) + bm0 + m)) * 1024 + n0 + n] = c * s_w[m];
                } else {
                    out[(size_t)(out_row0 + bm0 + m) * 1024 + n0 + n] = c;
                }
            }
}

// ---------------- host launcher ----------------

extern "C" void kernel_launch(void* const* d_in, const int* in_sizes, int n_in,
                              void* d_out, int out_size, void* d_ws, size_t ws_size,
                              hipStream_t stream) {
    const float* hidden   = (const float*)d_in[0];
    const float* hsu      = (const float*)d_in[1];
    const float* timestep = (const float*)d_in[2];
    const float* gate_w   = (const float*)d_in[3];
    const float* gate_up  = (const float*)d_in[4];
    const float* down     = (const float*)d_in[5];
    const float* sh_gu    = (const float*)d_in[6];
    const float* sh_dn    = (const float*)d_in[7];
    float* out = (float*)d_out;

    char* p = (char*)d_ws;
    auto alloc = [&](size_t bytes) { char* r = p; p += (bytes + 255) & ~(size_t)255; return r; };
    float* scores    = (float*)alloc((size_t)Bb * Ee * Ss * 4);
    int*   sel_idx   = (int*)  alloc((size_t)Bb * Ee * CAPk * 4);
    float* sel_gate  = (float*)alloc((size_t)Bb * Ee * CAPk * 4);
    float* sums      = (float*)alloc((size_t)Bb * Ss * 4);
    int*   slot_token= (int*)  alloc((size_t)Ee * Bb * CAPk * 4);
    float* slot_w    = (float*)alloc((size_t)Ee * Bb * CAPk * 4);
    int*   cnt       = (int*)  alloc((size_t)Bb * Ss * 4);
    int*   inv       = (int*)  alloc((size_t)Bb * Ss * 16 * 4);
    u16*   Xb        = (u16*)  alloc((size_t)16384 * 1024 * 2);   // hidden in bf16 (32 MB)
    char* phase = p;
    long long avail = (long long)((char*)d_ws + ws_size - phase);
    if (avail < 0) avail = 0;

    const long long eo_bytes     = (long long)32768 * 1024 * 4;                    // 134 MB
    const long long per_e        = ((long long)2048 * 1024 + 1024 * 1024 +
                                    (long long)2048 * 1024) * 2;                   // 10 MB (Wt1r+Wt2r+actR)
    const long long shared_fixed = ((long long)2048 * 1024 + 1024 * 1024) * 2;     // 6 MB (Wt1s+Wt2s)

    // --- independent prep + router ---
    convert_bf16<<<16384, 256, 0, stream>>>(hidden, Xb);
    router_scores<<<(Bb * Ss) / 64, 256, 0, stream>>>(hsu, gate_w, timestep, scores);
    topk_kernel<<<Bb * Ee, 256, 0, stream>>>(scores, sel_idx, sel_gate);
    zero2_kernel<<<(Bb * Ss) / 256, 256, 0, stream>>>(sums, cnt);
    accum_kernel<<<(Bb * Ee * CAPk) / 256, 256, 0, stream>>>(sel_idx, sel_gate, sums);
    finalize_kernel<<<(Bb * Ee * CAPk) / 256, 256, 0, stream>>>(sel_idx, sel_gate, sums,
                                                                slot_token, slot_w, cnt, inv);

    long long min_shared = shared_fixed + (long long)128 * 2048;   // + 128 act rows
    bool use_eo = (avail >= eo_bytes + (per_e > min_shared ? per_e : min_shared));

    if (use_eo) {
        float* eo = (float*)phase;
        char* ph2 = phase + eo_bytes;
        long long avail2 = avail - eo_bytes;

        // --- routed experts: gather fused into gemm1 A-stage; gemm2 writes dense eo ---
        {
            int g = (int)(avail2 / per_e);
            if (g < 1) g = 1;
            if (g > Ee) g = Ee;
            u16* Wt1r = (u16*)ph2;
            u16* Wt2r = Wt1r + (size_t)g * 2048 * 1024;
            u16* actR = Wt2r + (size_t)g * 1024 * 1024;

            for (int e0 = 0; e0 < Ee; e0 += g) {
                int cg = Ee - e0; if (cg > g) cg = g;
                transpose_bf16<<<dim3(32, 16, cg), 256, 0, stream>>>(
                    gate_up + (size_t)e0 * 2097152, Wt1r, 2048, 2097152, 2097152);
                transpose_bf16<<<dim3(16, 16, cg), 256, 0, stream>>>(
                    down + (size_t)e0 * 1048576, Wt2r, 1024, 1048576, 1048576);
                gemm1_mfma<true, true><<<dim3(8, 16, cg), 256, 0, stream>>>(
                    Xb, 0, 2048, Wt1r, actR, slot_token, e0);
                gemm2_mfma<2><<<dim3(8, 16, cg), 256, 0, stream>>>(
                    actR, 2048, Wt2r, slot_token, slot_w, eo, 0, e0);
            }
        }

        // --- shared expert: plain stores to out ---
        {
            u16* Wt1s = (u16*)ph2;
            u16* Wt2s = Wt1s + (size_t)2048 * 1024;
            u16* actS = Wt2s + (size_t)1024 * 1024;
            long long room = (avail2 - shared_fixed) / 2048;   // act rows
            room &= ~127LL;
            int R = (int)(room > 16384 ? 16384 : room);
            if (R < 128) R = 128;

            transpose_bf16<<<dim3(32, 16, 1), 256, 0, stream>>>(sh_gu, Wt1s, 2048, 0, 0);
            transpose_bf16<<<dim3(16, 16, 1), 256, 0, stream>>>(sh_dn, Wt2s, 1024, 0, 0);
            for (int r0 = 0; r0 < Bb * Ss; r0 += R) {
                int cur = Bb * Ss - r0; if (cur > R) cur = R;
                gemm1_mfma<false, false><<<dim3(8, cur / 128, 1), 256, 0, stream>>>(
                    Xb, r0, 0, Wt1s, actS, nullptr, 0);
                gemm2_mfma<0><<<dim3(8, cur / 128, 1), 256, 0, stream>>>(
                    actS, 0, Wt2s, nullptr, nullptr, out, r0, 0);
            }
        }

        // --- dense combine (high occupancy, vectorized) ---
        combine_kernel<<<Bb * Ss, 256, 0, stream>>>(cnt, inv, eo, out);
    } else {
        // --- legacy fallback: shared phase writes out, routed scatters atomically ---
        {
            u16* Wt1s = (u16*)phase;
            u16* Wt2s = Wt1s + (size_t)2048 * 1024;
            u16* actS = Wt2s + (size_t)1024 * 1024;
            long long room = (avail - shared_fixed) / 2048;
            room &= ~127LL;
            int R = (int)(room > 16384 ? 16384 : room);
            if (R < 128) R = 128;

            transpose_bf16<<<dim3(32, 16, 1), 256, 0, stream>>>(sh_gu, Wt1s, 2048, 0, 0);
            transpose_bf16<<<dim3(16, 16, 1), 256, 0, stream>>>(sh_dn, Wt2s, 1024, 0, 0);
            for (int r0 = 0; r0 < Bb * Ss; r0 += R) {
                int cur = Bb * Ss - r0; if (cur > R) cur = R;
                gemm1_mfma<false, false><<<dim3(8, cur / 128, 1), 256, 0, stream>>>(
                    Xb, r0, 0, Wt1s, actS, nullptr, 0);
                gemm2_mfma<0><<<dim3(8, cur / 128, 1), 256, 0, stream>>>(
                    actS, 0, Wt2s, nullptr, nullptr, out, r0, 0);
            }
        }
        {
            int g = (int)(avail / per_e);
            if (g < 1) g = 1;
            if (g > Ee) g = Ee;
            u16* Wt1r = (u16*)phase;
            u16* Wt2r = Wt1r + (size_t)g * 2048 * 1024;
            u16* actR = Wt2r + (size_t)g * 1024 * 1024;

            for (int e0 = 0; e0 < Ee; e0 += g) {
                int cg = Ee - e0; if (cg > g) cg = g;
                transpose_bf16<<<dim3(32, 16, cg), 256, 0, stream>>>(
                    gate_up + (size_t)e0 * 2097152, Wt1r, 2048, 2097152, 2097152);
                transpose_bf16<<<dim3(16, 16, cg), 256, 0, stream>>>(
                    down + (size_t)e0 * 1048576, Wt2r, 1024, 1048576, 1048576);
                gemm1_mfma<true, true><<<dim3(8, 16, cg), 256, 0, stream>>>(
                    Xb, 0, 2048, Wt1r, actR, slot_token, e0);
                gemm2_mfma<1><<<dim3(8, 16, cg), 256, 0, stream>>>(
                    actR, 2048, Wt2r, slot_token, slot_w, out, 0, e0);
            }
        }
    }
}